// Round 14
// baseline (59.038 us; speedup 1.0000x reference)
//
#include <hip/hip_runtime.h>
#include <hip/hip_bf16.h>
#include <hip/hip_fp8.h>
#include <stdint.h>

// VQ: z (32,256,32,32) f32 NCHW, codebook (1024,256) f32
// out: z_q (8388608 f32 NCHW) + commit_loss (1 f32 at out[8388608])
//
// R14: R10's fast shape (quarter codebook, stage-ONCE, barrier-free main
// loop, 512x512 = 2 blocks/CU = 16 waves/CU — the only config that beat
// 60us) upgraded:
//  - 32x32x16 fp8 MFMA: one A-b128 feeds 32x32 (per-CU ds_read floor
//    10.2us -> 5.1us; MFMA instrs halved; 1 shfl merge not 2).
//  - k3 fused into k2 (last-block finisher, proven R11/R12).
// A and B use the SAME k-permutation (ks*16 + h*8 + j, h=lane>>5) so the
// MFMA dot-product is invariant to the packing bijection; C/D layout is
// the HW-verified col=lane&31, row=(r&3)+8*(r>>2)+4*h.
// Numerics otherwise identical to passing R9/R10 (fp8 e4m3 x-512, encoded
// argmin (S&~0x3FF)|code, loss = 1.25*(sum z^2 + sum minS)/N).

#define WS_CN    0                 // 1024 f32 (4KB)
#define WS_CB    4096              // 256 KB fp8 frags
#define WS_PENC  266240            // 4*32768 f32 = 512 KB
#define WS_PART2 790528            // 128 f32 (z^2 partials)
#define WS_PART  791040            // 512 f32 (minS partials)
#define WS_CTR   793088            // 1 u32

typedef float f32x4  __attribute__((ext_vector_type(4)));
typedef float f32x16 __attribute__((ext_vector_type(16)));
typedef long  i64;
typedef long  l64x2 __attribute__((ext_vector_type(2)));

template <bool HI>
static __device__ __forceinline__ unsigned pk2(float a, float b, unsigned old) {
#if __has_builtin(__builtin_amdgcn_cvt_pk_fp8_f32)
    return (unsigned)__builtin_amdgcn_cvt_pk_fp8_f32(a, b, (int)old, HI);
#else
    __hip_fp8_e4m3 qa(a), qb(b);
    unsigned w = (unsigned)qa.__x | ((unsigned)qb.__x << 8);
    return HI ? ((old & 0x0000FFFFu) | (w << 16)) : ((old & 0xFFFF0000u) | w);
#endif
}

// ---------------- K0: cnorm*256 + (-512*codebook) fp8 32x32-fragment-ordered ----------------
// Quarter q, code-group g (32 codes), unit m (ks pair): 16B per lane at
// byteoff = q*65536 + ((g*8+m)*64 + h*32 + r32)*16 + (ks&1)*8 + (l&1)*4
// where lane = h*32 + r32 holds A[row=r32][k = ks*16 + h*8 + j].
__global__ __launch_bounds__(64) void k0_prep(const float* __restrict__ cb,
                                              float* __restrict__ cn256,
                                              unsigned char* __restrict__ cbf8,
                                              unsigned* __restrict__ ctr) {
    const int code = blockIdx.x;
    const int l = threadIdx.x;
    if (code == 0 && l == 0) *ctr = 0u;
    const float4 v = ((const float4*)cb)[code * 64 + l];   // k = 4l..4l+3
    float nrm = v.x * v.x + v.y * v.y + v.z * v.z + v.w * v.w;
    #pragma unroll
    for (int off = 1; off < 64; off <<= 1) nrm += __shfl_xor(nrm, off);
    if (l == 0) cn256[code] = 256.f * nrm;
    unsigned u = pk2<false>(-512.f * v.x, -512.f * v.y, 0u);
    u = pk2<true>(-512.f * v.z, -512.f * v.w, u);
    const int q = code >> 8, cl_ = code & 255;
    const int g = cl_ >> 5, r32 = cl_ & 31;
    const int m = l >> 3;                 // ks pair (ks = l>>2)
    const int sel8 = (l >> 2) & 1;        // ks & 1
    const int h = (l >> 1) & 1;           // (k>>3)&1
    const int byteoff = q * 65536 + ((g * 8 + m) * 64 + h * 32 + r32) * 16
                      + sel8 * 8 + (l & 1) * 4;
    *(unsigned*)(cbf8 + byteoff) = u;
}

// ---------------- K1: per-quarter distances (32x32x16 fp8 MFMA) + encoded argmin ----------------
__global__ __launch_bounds__(512) void k1_main(const float* __restrict__ z,
                                               const unsigned char* __restrict__ cbf8,
                                               const float* __restrict__ cn256,
                                               float* __restrict__ penc,
                                               float* __restrict__ part2) {
    __shared__ __align__(16) unsigned char lds[65536];
    __shared__ __align__(16) float cnl[256];
    __shared__ float redz[8];
    const int t = threadIdx.x, w = t >> 6, l = t & 63;
    const int h = l >> 5, h4 = h * 4, p32 = l & 31;
    const int b = blockIdx.x, q = b >> 7, grp = b & 127;
    const int img = grp >> 2, hw0 = (grp & 3) << 8;        // 256 pos per group
    const unsigned qbase = (unsigned)(q * 256);

    // stage quarter (64 KB) + quarter norms (1 KB) -> LDS, stage-ONCE
    {
        const unsigned char* src = cbf8 + q * 65536;
        #pragma unroll
        for (int i = 0; i < 8; ++i) {
            const int off = i * 8192 + w * 1024;
            __builtin_amdgcn_global_load_lds(
                (const __attribute__((address_space(1))) unsigned*)(src + off + l * 16),
                (__attribute__((address_space(3))) unsigned*)(lds + off), 16, 0, 0);
        }
        if (w == 0) {
            const unsigned char* csrc = (const unsigned char*)(cn256 + q * 256);
            __builtin_amdgcn_global_load_lds(
                (const __attribute__((address_space(1))) unsigned*)(csrc + l * 16),
                (__attribute__((address_space(3))) unsigned*)((unsigned char*)cnl), 16, 0, 0);
        }
    }

    // z -> fp8 B-frags for 32x32x16: lane holds z[pos=p32][k=ks*16+h*8+j]
    const float* zp = z + img * 262144 + hw0 + w * 32 + p32;
    float z2 = 0.f;
    i64 zf[16];
    #pragma unroll
    for (int ks = 0; ks < 16; ++ks) {
        const float* s0 = zp + (ks * 16 + h * 8) * 1024;
        float v0 = s0[0], v1 = s0[1024], v2 = s0[2048], v3 = s0[3072];
        float v4 = s0[4096], v5 = s0[5120], v6 = s0[6144], v7 = s0[7168];
        z2 += v0*v0 + v1*v1 + v2*v2 + v3*v3 + v4*v4 + v5*v5 + v6*v6 + v7*v7;
        unsigned lo = pk2<false>(v0, v1, 0u); lo = pk2<true>(v2, v3, lo);
        unsigned hi = pk2<false>(v4, v5, 0u); hi = pk2<true>(v6, v7, hi);
        zf[ks] = (i64)(((unsigned long)hi << 32) | (unsigned long)lo);
    }
    __syncthreads();   // staging resident; main loop is barrier-free

    float menc = __builtin_bit_cast(float, 0x7F7FFC00u);

#define ENC(g, acc) do {                                                         \
    _Pragma("unroll") for (int rr = 0; rr < 4; ++rr) {                           \
        const f32x4 cn = *(const f32x4*)(cnl + (g) * 32 + rr * 8 + h4);          \
        _Pragma("unroll") for (int r2 = 0; r2 < 4; ++r2) {                       \
            const float s = (acc)[rr * 4 + r2] + cn[r2];                         \
            const unsigned e = (__builtin_bit_cast(unsigned, s) & 0xFFFFFC00u)   \
                             | (qbase + (unsigned)((g) * 32 + rr * 8 + h4 + r2));\
            menc = fminf(menc, __builtin_bit_cast(float, e));                    \
        }                                                                        \
    }                                                                            \
} while (0)

    #pragma unroll
    for (int gp = 0; gp < 4; ++gp) {
        const int ga = gp * 2, gb = ga + 1;
        f32x16 accA = {0.f,0.f,0.f,0.f,0.f,0.f,0.f,0.f,0.f,0.f,0.f,0.f,0.f,0.f,0.f,0.f};
        f32x16 accB = {0.f,0.f,0.f,0.f,0.f,0.f,0.f,0.f,0.f,0.f,0.f,0.f,0.f,0.f,0.f,0.f};
        #pragma unroll
        for (int m = 0; m < 8; ++m) {
            const l64x2 ua = *(const l64x2*)(lds + ((ga * 8 + m) * 64 + l) * 16);
            const l64x2 ub = *(const l64x2*)(lds + ((gb * 8 + m) * 64 + l) * 16);
            accA = __builtin_amdgcn_mfma_f32_32x32x16_fp8_fp8(ua.x, zf[2 * m],     accA, 0, 0, 0);
            accB = __builtin_amdgcn_mfma_f32_32x32x16_fp8_fp8(ub.x, zf[2 * m],     accB, 0, 0, 0);
            accA = __builtin_amdgcn_mfma_f32_32x32x16_fp8_fp8(ua.y, zf[2 * m + 1], accA, 0, 0, 0);
            accB = __builtin_amdgcn_mfma_f32_32x32x16_fp8_fp8(ub.y, zf[2 * m + 1], accB, 0, 0, 0);
        }
        ENC(ga, accA);
        ENC(gb, accB);
    }
#undef ENC

    // lane covers 16 rows (its h); complement rows live on lane^32
    menc = fminf(menc, __shfl_xor(menc, 32));
    const int pos = grp * 256 + w * 32 + p32;
    if (l < 32) penc[q * 32768 + pos] = menc;

    // z^2 partial (q==0 blocks only contribute; z identical across quarters)
    #pragma unroll
    for (int off = 1; off < 64; off <<= 1) z2 += __shfl_xor(z2, off);
    if (l == 0) redz[w] = z2;
    __syncthreads();
    if (t == 0 && q == 0) {
        float s = 0.f;
        #pragma unroll
        for (int i = 0; i < 8; ++i) s += redz[i];
        part2[grp] = s;
    }
}

// ---------------- K2: 4-way merge + z_q gather/transpose/write + loss (last-block finisher) ----------------
__global__ __launch_bounds__(256) void k2_out(const float* __restrict__ cbf,
                                              const float* __restrict__ penc,
                                              float* __restrict__ out,
                                              float* __restrict__ part,
                                              const float* __restrict__ part2,
                                              unsigned* __restrict__ ctr) {
    __shared__ __align__(16) float zqbuf[32 * 260];
    __shared__ unsigned idxl[64];
    __shared__ unsigned lastflag;
    const int t = threadIdx.x, b = blockIdx.x;
    const int pos0 = b * 64, img = pos0 >> 10, hw0 = pos0 & 1023;

    if (t < 64) {
        const int pos = pos0 + t;
        const float e = fminf(fminf(penc[pos], penc[32768 + pos]),
                              fminf(penc[65536 + pos], penc[98304 + pos]));
        const unsigned eu = __builtin_bit_cast(unsigned, e);
        idxl[t] = eu & 0x3FFu;
        float myS = __builtin_bit_cast(float, eu & 0xFFFFFC00u);
        #pragma unroll
        for (int off = 1; off < 64; off <<= 1) myS += __shfl_xor(myS, off);
        if (t == 0) part[b] = myS * (1.f / 256.f);
    }

    const float4* cb4 = (const float4*)cbf;
    for (int hh = 0; hh < 2; ++hh) {
        __syncthreads();
        #pragma unroll
        for (int i = 0; i < 8; ++i) {
            const int flat = i * 256 + t;        // [0,2048)
            const int p = flat >> 6;             // row 0..31
            const int qq = flat & 63;            // float4 index
            const unsigned code = idxl[hh * 32 + p];
            *(float4*)&zqbuf[p * 260 + qq * 4] = cb4[code * 64 + qq];
        }
        __syncthreads();
        const int p = t & 31, c0 = t >> 5;       // c0 0..7
        float* ob = out + img * 262144 + hw0 + hh * 32 + p;
        #pragma unroll
        for (int cc = 0; cc < 32; ++cc) {
            const int ch = c0 + cc * 8;
            ob[ch * 1024] = zqbuf[p * 260 + ch];
        }
    }

    // last-block deterministic loss finisher
    if (t == 0) {
        __threadfence();
        lastflag = (atomicAdd(ctr, 1u) == 511u) ? 1u : 0u;
    }
    __syncthreads();
    if (lastflag) {
        __threadfence();
        float* red2 = zqbuf;                     // reuse LDS
        float v = part[t] + part[t + 256];
        if (t < 128) v += part2[t];
        red2[t] = v;
        __syncthreads();
        #pragma unroll
        for (int off = 128; off > 0; off >>= 1) {
            if (t < off) red2[t] += red2[t + off];
            __syncthreads();
        }
        if (t == 0) out[8388608] = 1.25f * red2[0] / 8388608.f;
    }
}

extern "C" void kernel_launch(void* const* d_in, const int* in_sizes, int n_in,
                              void* d_out, int out_size, void* d_ws, size_t ws_size,
                              hipStream_t stream) {
    const float* z  = (const float*)d_in[0];
    const float* cb = (const float*)d_in[1];
    float* out = (float*)d_out;
    unsigned char* ws = (unsigned char*)d_ws;
    float* cn256 = (float*)(ws + WS_CN);
    unsigned char* cbf8 = ws + WS_CB;
    float* penc  = (float*)(ws + WS_PENC);
    float* part2 = (float*)(ws + WS_PART2);
    float* part  = (float*)(ws + WS_PART);
    unsigned* ctr = (unsigned*)(ws + WS_CTR);

    hipLaunchKernelGGL(k0_prep, dim3(1024), dim3(64), 0, stream, cb, cn256, cbf8, ctr);
    hipLaunchKernelGGL(k1_main, dim3(512), dim3(512), 0, stream, z, cbf8, cn256, penc, part2);
    hipLaunchKernelGGL(k2_out,  dim3(512), dim3(256), 0, stream, cb, penc, out, part, part2, ctr);
}